// Round 6
// baseline (444.895 us; speedup 1.0000x reference)
//
#include <hip/hip_runtime.h>

// CIN fused kernel, round 6: mfma_f32_32x32x16_f16, 3-waves/SIMD occupancy.
// History: r4 (256thr/NB16, 2 blk/CU, 2 w/SIMD, 256-reg cap) = 207us,
// MfmaUtil 46%, 6.7MB residual spill. r5 (512thr, 128-reg cap) = spill
// disaster (66MB scratch). Working set is ~150-170 regs/wave -> the tier
// that fits is 3 waves/SIMD (170-reg cap). This round: NB=8, 256-thr block,
// 4 waves, each wave = 1 m-tile (2 batches) x 4 n-tiles; LDS 28.7KB -> LDS
// allows 5 blk/CU, regs bind at 3 blk/CU = 12 waves/CU (1.5x r4's hiding).
// GEMM: M = B*16 (m = batch*16+d), N = 128, K = i*64+j (layer-0 zero-padded).
// B-frags stream from L2/L1 in pre-swizzled frag order -> no K-loop barriers.
// Layer-0 K=16 sparsity via three static i-ranges: 84 of 156 k-steps.

#define F0N 39
#define NC16 156                              // K/16 per layer
#define LAYER_HALVES (NC16 * 4 * 64 * 8)      // 319488 f16 per layer

typedef _Float16 half8 __attribute__((ext_vector_type(8)));
typedef float f32x16 __attribute__((ext_vector_type(16)));

// ---- prep: swizzle filters into 32x32x16 B-fragment order, f16 ----
// fprep[l][c16][nt][lane][reg] = F_l[row(kg), nt*32 + (lane&31)],
// kg = c16*16 + (lane>>5)*8 + reg; layer0 row = i*39+j (j=kg&63), 0 if j>=39.
__global__ void prep_kernel(const float* __restrict__ f0,
                            const float* __restrict__ f1,
                            const float* __restrict__ f2,
                            _Float16* __restrict__ fprep) {
    int blk  = blockIdx.x;            // l*NC16 + c16
    int l    = blk / NC16;
    int c16  = blk - l * NC16;
    int t    = threadIdx.x;
    int nt   = t >> 6;
    int lane = t & 63;
    int hf   = lane >> 5;
    int n    = nt * 32 + (lane & 31);
    const float* f = (l == 0) ? f0 : ((l == 1) ? f1 : f2);
    half8 v;
    #pragma unroll
    for (int reg = 0; reg < 8; ++reg) {
        int kg = c16 * 16 + hf * 8 + reg;
        float x;
        if (l == 0) {
            int fi = kg >> 6, fj = kg & 63;
            x = (fj < F0N) ? f[(fi * F0N + fj) * 128 + n] : 0.0f;
        } else {
            x = f[(size_t)kg * 128 + n];
        }
        v[reg] = (_Float16)x;
    }
    *(half8*)&fprep[(size_t)l * LAYER_HALVES + (((c16 * 4 + nt) * 64 + lane) << 3)] = v;
}

// One K=16 step, Q is a LITERAL (keeps hreg indexing static).
#define LOAD_BF(C16)                                                          \
    half8 Bf[4];                                                              \
    {                                                                         \
        _Pragma("unroll")                                                     \
        for (int nt = 0; nt < 4; ++nt)                                        \
            Bf[nt] = *(const half8*)(fpl + ((((C16) * 4 + nt) * 64 + lane) << 3)); \
    }

#define DO_MFMA()                                                             \
    {                                                                         \
        _Pragma("unroll")                                                     \
        for (int nt = 0; nt < 4; ++nt)                                        \
            acc[nt] = __builtin_amdgcn_mfma_f32_32x32x16_f16(                 \
                Afr, Bf[nt], acc[nt], 0, 0, 0);                               \
    }

#define FULL_STEP(Q)                                                          \
    do {                                                                      \
        LOAD_BF(i * 4 + (Q));                                                 \
        half8 Afr = hreg[(Q)] * xv2;                                          \
        DO_MFMA();                                                            \
    } while (0)

// partial: zero elements with j <= i (j = Q*16 + hf*8 + reg)
#define PART_STEP(Q)                                                          \
    do {                                                                      \
        LOAD_BF(i * 4 + (Q));                                                 \
        const int j0 = (Q) * 16 + hf * 8;                                     \
        half8 msk;                                                            \
        _Pragma("unroll")                                                     \
        for (int reg = 0; reg < 8; ++reg)                                     \
            msk[reg] = (j0 + reg > i) ? (_Float16)1.0f : (_Float16)0.0f;      \
        half8 Afr = hreg[(Q)] * (msk * xv2);                                  \
        DO_MFMA();                                                            \
    } while (0)

__global__ __launch_bounds__(256, 3) void cin_mfma(
    const float* __restrict__ xin,     // (B, 624) fp32
    const _Float16* __restrict__ fprep,
    const float* __restrict__ wnn,     // (256)
    const float* __restrict__ bnn,     // (1)
    float* __restrict__ out)           // (B)
{
    __shared__ _Float16 hT[8 * 16 * 72] __attribute__((aligned(16)));  // [nb][d][j pad72] 18432 B
    __shared__ _Float16 xs[8 * 16 * 40] __attribute__((aligned(16)));  // [nb][d][i pad40] 10240 B
    __shared__ float outacc[8];

    const int t     = threadIdx.x;
    const int wave  = t >> 6;        // 0..3
    const int lane  = t & 63;
    const int hf    = lane >> 5;     // k-half within 16-chunk
    const int lane5 = lane & 31;
    const int dl    = lane & 15;     // d for A-side
    const int bt    = lane5 >> 4;    // A-side batch within 32-row m-tile
    const int nb0   = wave * 2;      // wave's first batch (local)
    const int b0    = blockIdx.x * 8;

    // zero hT (j-pad must be 0: layer-0 h-runs read j up to 63)
    for (int u = t; u < 1152; u += 256) ((uint4*)hT)[u] = uint4{0, 0, 0, 0};
    if (t < 8) outacc[t] = 0.0f;
    __syncthreads();

    // stage x0 -> hT (layer-0 hidden, [nb][d][j=i]) and xs ([nb][d][i])
    for (int u = t; u < 8 * F0N; u += 256) {
        int nb = u / F0N;
        int i  = u - nb * F0N;
        const float* src = xin + (size_t)(b0 + nb) * 624 + i * 16;
        #pragma unroll
        for (int q = 0; q < 4; ++q) {
            float4 v = *(const float4*)(src + q * 4);
            int d = q * 4;
            hT[(nb * 16 + d + 0) * 72 + i] = (_Float16)v.x;
            hT[(nb * 16 + d + 1) * 72 + i] = (_Float16)v.y;
            hT[(nb * 16 + d + 2) * 72 + i] = (_Float16)v.z;
            hT[(nb * 16 + d + 3) * 72 + i] = (_Float16)v.w;
            xs[(nb * 16 + d + 0) * 40 + i] = (_Float16)v.x;
            xs[(nb * 16 + d + 1) * 40 + i] = (_Float16)v.y;
            xs[(nb * 16 + d + 2) * 40 + i] = (_Float16)v.z;
            xs[(nb * 16 + d + 3) * 40 + i] = (_Float16)v.w;
        }
    }
    __syncthreads();

    const int arow  = (nb0 + bt) * 16 + dl;   // this lane's A-row (local)
    const int xrow0 = arow * 40;

    for (int layer = 0; layer < 3; ++layer) {
        // lane's A row: m = lane5 -> batch nb0+bt, d = dl.
        // j runs r*16 + hf*8 .. +8 for r = 0..3 -> 4 half8.
        half8 hreg[4];
        {
            int base = arow * 72 + hf * 8;
            #pragma unroll
            for (int r = 0; r < 4; ++r)
                hreg[r] = *(const half8*)&hT[base + r * 16];
        }
        __syncthreads();   // h-regs loaded before epilogue may overwrite hT

        f32x16 acc[4];
        #pragma unroll
        for (int nt = 0; nt < 4; ++nt)
            #pragma unroll
            for (int e = 0; e < 16; ++e) acc[nt][e] = 0.0f;

        const _Float16* fpl = fprep + (size_t)layer * LAYER_HALVES;

        if (layer == 0) {
            // K = i*64+j, j>i, j<39 (j>=39 -> zero filter, harmless).
            // i in [0,16): q0 partial (skip i==15), q1 full, q2 full
            for (int i = 0; i < 16; ++i) {
                _Float16 xv2 = (_Float16)2.0f * xs[xrow0 + i];
                if (i < 15) PART_STEP(0);
                FULL_STEP(1);
                FULL_STEP(2);
            }
            // i in [16,32): q1 partial (skip i==31), q2 full
            for (int i = 16; i < 32; ++i) {
                _Float16 xv2 = (_Float16)2.0f * xs[xrow0 + i];
                if (i < 31) PART_STEP(1);
                FULL_STEP(2);
            }
            // i in [32,38): q2 partial
            for (int i = 32; i < 38; ++i) {
                _Float16 xv2 = (_Float16)2.0f * xs[xrow0 + i];
                PART_STEP(2);
            }
        } else {
            for (int i = 0; i < F0N; ++i) {
                _Float16 xv2 = xs[xrow0 + i];
                FULL_STEP(0);
                FULL_STEP(1);
                FULL_STEP(2);
                FULL_STEP(3);
            }
        }

        // ---- epilogue ----
        // C/D layout: col n = nt*32 + lane5; row = (reg&3) + 8*(reg>>2) + 4*hf;
        // batch_in_tile = reg>>3, d = (reg&3) + 8*((reg>>2)&1) + 4*hf.
        const int catbase = (layer == 2) ? 128 : ((layer == 0) ? -64 : 0);
        {
            float cm0 = 0.0f, cm1 = 0.0f;
            #pragma unroll
            for (int nt = 0; nt < 4; ++nt) {
                float r[16];
                #pragma unroll
                for (int reg = 0; reg < 16; ++reg)
                    r[reg] = fmaxf(acc[nt][reg], 0.0f);
                if (layer < 2 && nt < 2) {         // next hidden: cols 0..63
                    const int j = nt * 32 + lane5;
                    #pragma unroll
                    for (int reg = 0; reg < 16; ++reg) {
                        int nb = nb0 + (reg >> 3);
                        int d  = (reg & 3) + 8 * ((reg >> 2) & 1) + 4 * hf;
                        hT[(nb * 16 + d) * 72 + j] = (_Float16)r[reg];
                    }
                }
                if (layer == 2 || nt >= 2) {       // direct-out readout
                    const float w = 1.0f + wnn[catbase + nt * 32 + lane5];
                    float s0 = ((r[0] + r[1]) + (r[2] + r[3])) +
                               ((r[4] + r[5]) + (r[6] + r[7]));
                    float s1 = ((r[8] + r[9]) + (r[10] + r[11])) +
                               ((r[12] + r[13]) + (r[14] + r[15]));
                    s0 += __shfl_xor(s0, 32, 64);  // combine hf halves (full d-sum)
                    s1 += __shfl_xor(s1, 32, 64);
                    cm0 = fmaf(s0, w, cm0);
                    cm1 = fmaf(s1, w, cm1);
                }
            }
            #pragma unroll
            for (int sh = 16; sh >= 1; sh >>= 1) {
                cm0 += __shfl_xor(cm0, sh, 64);
                cm1 += __shfl_xor(cm1, sh, 64);
            }
            if (lane == 0) {
                atomicAdd(&outacc[nb0], cm0);
                atomicAdd(&outacc[nb0 + 1], cm1);
            }
        }
        __syncthreads();   // hT(next hidden) + outacc visible
    }

    if (t < 8) out[b0 + t] = outacc[t] + bnn[0];
}

extern "C" void kernel_launch(void* const* d_in, const int* in_sizes, int n_in,
                              void* d_out, int out_size, void* d_ws, size_t ws_size,
                              hipStream_t stream) {
    const float* xin = (const float*)d_in[0];
    const float* f0g = (const float*)d_in[1];
    const float* f1g = (const float*)d_in[2];
    const float* f2g = (const float*)d_in[3];
    const float* wnn = (const float*)d_in[4];
    const float* bnn = (const float*)d_in[5];
    float* out = (float*)d_out;
    _Float16* fprep = (_Float16*)d_ws;   // 3 * 319488 * 2 B = 1.83 MB

    prep_kernel<<<3 * NC16, 256, 0, stream>>>(f0g, f1g, f2g, fprep);

    const int B = in_sizes[0] / 624;     // 8192
    cin_mfma<<<B / 8, 256, 0, stream>>>(xin, fprep, wnn, bnn, out);
}

// Round 7
// 300.325 us; speedup vs baseline: 1.4814x; 1.4814x over previous
//
#include <hip/hip_runtime.h>

// CIN fused kernel, round 7: mfma_f32_32x32x16_f16, 2m x 2n tiles, 3 w/SIMD.
// Ladder: r2 16x16 243us/47%; r4 (2m x 4n, 256-cap) 207us/46% + 6.7MB spill;
// r5 (128-cap) spill disaster; r6 (1m x 4n, 170-cap) 395us — arch regs
// (Bf 16+16 pipelined + hreg) overflowed the ~106 arch budget left by 64 AGPR.
// Fix: 2m x 2n per wave -> acc 64 AGPR, hreg 32, Bf 8(+8 pipe) -> arch ~85.
// Fits launch_bounds(256,3) => 3 blocks/CU = 12 waves/CU, spill-free, and
// MFMA:load = 4 mfma (129cy) : 2 loads, same as r4 but 1.5x the waves.
// GEMM: M = B*16 (m = batch*16+d), N = 128, K = i*64+j (layer-0 zero-padded).
// B-frags stream from L2/L1 in pre-swizzled frag order -> no K-loop barriers.
// Layer-0 K=16 sparsity via three static i-ranges: 84 of 156 k-steps.

#define F0N 39
#define NC16 156                              // K/16 per layer
#define LAYER_HALVES (NC16 * 4 * 64 * 8)      // 319488 f16 per layer

typedef _Float16 half8 __attribute__((ext_vector_type(8)));
typedef float f32x16 __attribute__((ext_vector_type(16)));

// ---- prep: swizzle filters into 32x32x16 B-fragment order, f16 ----
// fprep[l][c16][nt][lane][reg] = F_l[row(kg), nt*32 + (lane&31)],
// kg = c16*16 + (lane>>5)*8 + reg; layer0 row = i*39+j (j=kg&63), 0 if j>=39.
__global__ void prep_kernel(const float* __restrict__ f0,
                            const float* __restrict__ f1,
                            const float* __restrict__ f2,
                            _Float16* __restrict__ fprep) {
    int blk  = blockIdx.x;            // l*NC16 + c16
    int l    = blk / NC16;
    int c16  = blk - l * NC16;
    int t    = threadIdx.x;
    int nt   = t >> 6;
    int lane = t & 63;
    int hf   = lane >> 5;
    int n    = nt * 32 + (lane & 31);
    const float* f = (l == 0) ? f0 : ((l == 1) ? f1 : f2);
    half8 v;
    #pragma unroll
    for (int reg = 0; reg < 8; ++reg) {
        int kg = c16 * 16 + hf * 8 + reg;
        float x;
        if (l == 0) {
            int fi = kg >> 6, fj = kg & 63;
            x = (fj < F0N) ? f[(fi * F0N + fj) * 128 + n] : 0.0f;
        } else {
            x = f[(size_t)kg * 128 + n];
        }
        v[reg] = (_Float16)x;
    }
    *(half8*)&fprep[(size_t)l * LAYER_HALVES + (((c16 * 4 + nt) * 64 + lane) << 3)] = v;
}

// Per-wave fpl base already folds ng*2 n-tiles + lane: fragment for (c16, tt)
// is at fplw + c16*2048 + tt*512 (halves).
#define LOAD_BF(C16)                                                          \
    half8 Bf0 = *(const half8*)(fplw + (C16) * 2048);                         \
    half8 Bf1 = *(const half8*)(fplw + (C16) * 2048 + 512);

#define DO_MFMA()                                                             \
    acc00 = __builtin_amdgcn_mfma_f32_32x32x16_f16(Af0, Bf0, acc00, 0, 0, 0); \
    acc01 = __builtin_amdgcn_mfma_f32_32x32x16_f16(Af0, Bf1, acc01, 0, 0, 0); \
    acc10 = __builtin_amdgcn_mfma_f32_32x32x16_f16(Af1, Bf0, acc10, 0, 0, 0); \
    acc11 = __builtin_amdgcn_mfma_f32_32x32x16_f16(Af1, Bf1, acc11, 0, 0, 0);

#define FULL_STEP(Q)                                                          \
    do {                                                                      \
        LOAD_BF(i * 4 + (Q));                                                 \
        half8 Af0 = hreg0[(Q)] * xv0;                                         \
        half8 Af1 = hreg1[(Q)] * xv1;                                         \
        DO_MFMA();                                                            \
    } while (0)

// partial: zero elements with j <= i (j = Q*16 + hf*8 + reg)
#define PART_STEP(Q)                                                          \
    do {                                                                      \
        LOAD_BF(i * 4 + (Q));                                                 \
        const int j0 = (Q) * 16 + hf * 8;                                     \
        half8 msk;                                                            \
        _Pragma("unroll")                                                     \
        for (int reg = 0; reg < 8; ++reg)                                     \
            msk[reg] = (j0 + reg > i) ? (_Float16)1.0f : (_Float16)0.0f;      \
        half8 Af0 = hreg0[(Q)] * (msk * xv0);                                 \
        half8 Af1 = hreg1[(Q)] * (msk * xv1);                                 \
        DO_MFMA();                                                            \
    } while (0)

// Epilogue for one 32x32 acc tile (ACC), n-tile index TT (0/1 within wave),
// batches NB0 = base batch of this m-tile. Accumulates weighted d-sums into
// CM0/CM1 and writes next-hidden when ng==0 and layer<2.
#define EPILOGUE_TILE(ACC, TT, NB0, CM0, CM1)                                 \
    do {                                                                      \
        float r[16];                                                          \
        _Pragma("unroll")                                                     \
        for (int reg = 0; reg < 16; ++reg)                                    \
            r[reg] = fmaxf((ACC)[reg], 0.0f);                                 \
        if (layer < 2 && ng == 0) {                                           \
            const int j = (TT) * 32 + lane5;                                  \
            _Pragma("unroll")                                                 \
            for (int reg = 0; reg < 16; ++reg) {                              \
                int nb = (NB0) + (reg >> 3);                                  \
                int d  = (reg & 3) + 8 * ((reg >> 2) & 1) + 4 * hf;           \
                hT[(nb * 16 + d) * 72 + j] = (_Float16)r[reg];                \
            }                                                                 \
        }                                                                     \
        if (layer == 2 || ng == 1) {                                          \
            const float w = 1.0f + wnn[catbase + (ng * 2 + (TT)) * 32 + lane5]; \
            float s0 = ((r[0] + r[1]) + (r[2] + r[3])) +                      \
                       ((r[4] + r[5]) + (r[6] + r[7]));                       \
            float s1 = ((r[8] + r[9]) + (r[10] + r[11])) +                    \
                       ((r[12] + r[13]) + (r[14] + r[15]));                   \
            s0 += __shfl_xor(s0, 32, 64);                                     \
            s1 += __shfl_xor(s1, 32, 64);                                     \
            CM0 = fmaf(s0, w, CM0);                                           \
            CM1 = fmaf(s1, w, CM1);                                           \
        }                                                                     \
    } while (0)

__global__ __launch_bounds__(256, 3) void cin_mfma(
    const float* __restrict__ xin,     // (B, 624) fp32
    const _Float16* __restrict__ fprep,
    const float* __restrict__ wnn,     // (256)
    const float* __restrict__ bnn,     // (1)
    float* __restrict__ out)           // (B)
{
    __shared__ _Float16 hT[8 * 16 * 72] __attribute__((aligned(16)));  // [nb][d][j pad72] 18432 B
    __shared__ _Float16 xs[8 * 16 * 40] __attribute__((aligned(16)));  // [nb][d][i pad40] 10240 B
    __shared__ float outacc[8];

    const int t     = threadIdx.x;
    const int wave  = t >> 6;        // 0..3
    const int lane  = t & 63;
    const int hf    = lane >> 5;     // k-half within 16-chunk
    const int lane5 = lane & 31;
    const int dl    = lane & 15;     // d for A-side
    const int bt    = lane5 >> 4;    // A-side batch within 32-row m-tile
    const int mg    = wave >> 1;     // m-group: batches mg*4 .. +4
    const int ng    = wave & 1;      // n-half:  cols ng*64 .. +64
    const int b0    = blockIdx.x * 8;

    // zero hT (j-pad must be 0: layer-0 h-runs read j up to 63)
    for (int u = t; u < 1152; u += 256) ((uint4*)hT)[u] = uint4{0, 0, 0, 0};
    if (t < 8) outacc[t] = 0.0f;
    __syncthreads();

    // stage x0 -> hT (layer-0 hidden, [nb][d][j=i]) and xs ([nb][d][i])
    for (int u = t; u < 8 * F0N; u += 256) {
        int nb = u / F0N;
        int i  = u - nb * F0N;
        const float* src = xin + (size_t)(b0 + nb) * 624 + i * 16;
        #pragma unroll
        for (int q = 0; q < 4; ++q) {
            float4 v = *(const float4*)(src + q * 4);
            int d = q * 4;
            hT[(nb * 16 + d + 0) * 72 + i] = (_Float16)v.x;
            hT[(nb * 16 + d + 1) * 72 + i] = (_Float16)v.y;
            hT[(nb * 16 + d + 2) * 72 + i] = (_Float16)v.z;
            hT[(nb * 16 + d + 3) * 72 + i] = (_Float16)v.w;
            xs[(nb * 16 + d + 0) * 40 + i] = (_Float16)v.x;
            xs[(nb * 16 + d + 1) * 40 + i] = (_Float16)v.y;
            xs[(nb * 16 + d + 2) * 40 + i] = (_Float16)v.z;
            xs[(nb * 16 + d + 3) * 40 + i] = (_Float16)v.w;
        }
    }
    __syncthreads();

    // lane's two A-rows (m-tiles mt=0,1): batches mg*4 + mt*2 + bt, d = dl
    const int arow0 = (mg * 4 + bt) * 16 + dl;
    const int arow1 = (mg * 4 + 2 + bt) * 16 + dl;
    const int xrow0 = arow0 * 40;
    const int xrow1 = arow1 * 40;

    for (int layer = 0; layer < 3; ++layer) {
        // j runs r*16 + hf*8 .. +8 for r = 0..3 -> 4 half8 per m-tile.
        half8 hreg0[4], hreg1[4];
        {
            int base0 = arow0 * 72 + hf * 8;
            int base1 = arow1 * 72 + hf * 8;
            #pragma unroll
            for (int r = 0; r < 4; ++r) {
                hreg0[r] = *(const half8*)&hT[base0 + r * 16];
                hreg1[r] = *(const half8*)&hT[base1 + r * 16];
            }
        }
        __syncthreads();   // h-regs loaded before epilogue may overwrite hT

        f32x16 acc00, acc01, acc10, acc11;
        #pragma unroll
        for (int e = 0; e < 16; ++e) {
            acc00[e] = 0.0f; acc01[e] = 0.0f;
            acc10[e] = 0.0f; acc11[e] = 0.0f;
        }

        // wave's B base: n-tiles ng*2, ng*2+1; fragment (c16,tt) at
        // fplw + c16*2048 + tt*512
        const _Float16* fplw = fprep + (size_t)layer * LAYER_HALVES
                             + ng * 1024 + (lane << 3);

        if (layer == 0) {
            // K = i*64+j, j>i, j<39 (j>=39 -> zero filter, harmless).
            for (int i = 0; i < 16; ++i) {
                _Float16 xv0 = (_Float16)2.0f * xs[xrow0 + i];
                _Float16 xv1 = (_Float16)2.0f * xs[xrow1 + i];
                if (i < 15) PART_STEP(0);
                FULL_STEP(1);
                FULL_STEP(2);
            }
            for (int i = 16; i < 32; ++i) {
                _Float16 xv0 = (_Float16)2.0f * xs[xrow0 + i];
                _Float16 xv1 = (_Float16)2.0f * xs[xrow1 + i];
                if (i < 31) PART_STEP(1);
                FULL_STEP(2);
            }
            for (int i = 32; i < 38; ++i) {
                _Float16 xv0 = (_Float16)2.0f * xs[xrow0 + i];
                _Float16 xv1 = (_Float16)2.0f * xs[xrow1 + i];
                PART_STEP(2);
            }
        } else {
            for (int i = 0; i < F0N; ++i) {
                _Float16 xv0 = xs[xrow0 + i];
                _Float16 xv1 = xs[xrow1 + i];
                FULL_STEP(0);
                FULL_STEP(1);
                FULL_STEP(2);
                FULL_STEP(3);
            }
        }

        // ---- epilogue ----
        // C/D layout: col n = (ng*2+tt)*32 + lane5;
        // row = (reg&3) + 8*(reg>>2) + 4*hf -> batch_in_tile = reg>>3,
        // d = (reg&3) + 8*((reg>>2)&1) + 4*hf.
        const int catbase = (layer == 2) ? 128 : ((layer == 0) ? -64 : 0);
        {   // m-tile 0: batches mg*4, mg*4+1
            const int nb0 = mg * 4;
            float cm0 = 0.0f, cm1 = 0.0f;
            EPILOGUE_TILE(acc00, 0, nb0, cm0, cm1);
            EPILOGUE_TILE(acc01, 1, nb0, cm0, cm1);
            #pragma unroll
            for (int sh = 16; sh >= 1; sh >>= 1) {
                cm0 += __shfl_xor(cm0, sh, 64);
                cm1 += __shfl_xor(cm1, sh, 64);
            }
            if (lane == 0 && (layer == 2 || ng == 1)) {
                atomicAdd(&outacc[nb0], cm0);
                atomicAdd(&outacc[nb0 + 1], cm1);
            }
        }
        {   // m-tile 1: batches mg*4+2, mg*4+3
            const int nb0 = mg * 4 + 2;
            float cm0 = 0.0f, cm1 = 0.0f;
            EPILOGUE_TILE(acc10, 0, nb0, cm0, cm1);
            EPILOGUE_TILE(acc11, 1, nb0, cm0, cm1);
            #pragma unroll
            for (int sh = 16; sh >= 1; sh >>= 1) {
                cm0 += __shfl_xor(cm0, sh, 64);
                cm1 += __shfl_xor(cm1, sh, 64);
            }
            if (lane == 0 && (layer == 2 || ng == 1)) {
                atomicAdd(&outacc[nb0], cm0);
                atomicAdd(&outacc[nb0 + 1], cm1);
            }
        }
        __syncthreads();   // hT(next hidden) + outacc visible
    }

    if (t < 8) out[b0 + t] = outacc[t] + bnn[0];
}

extern "C" void kernel_launch(void* const* d_in, const int* in_sizes, int n_in,
                              void* d_out, int out_size, void* d_ws, size_t ws_size,
                              hipStream_t stream) {
    const float* xin = (const float*)d_in[0];
    const float* f0g = (const float*)d_in[1];
    const float* f1g = (const float*)d_in[2];
    const float* f2g = (const float*)d_in[3];
    const float* wnn = (const float*)d_in[4];
    const float* bnn = (const float*)d_in[5];
    float* out = (float*)d_out;
    _Float16* fprep = (_Float16*)d_ws;   // 3 * 319488 * 2 B = 1.83 MB

    prep_kernel<<<3 * NC16, 256, 0, stream>>>(f0g, f1g, f2g, fprep);

    const int B = in_sizes[0] / 624;     // 8192
    cin_mfma<<<B / 8, 256, 0, stream>>>(xin, fprep, wnn, bnn, out);
}